// Round 5
// baseline (674.055 us; speedup 1.0000x reference)
//
#include <hip/hip_runtime.h>
#include <math.h>

#define NROWS 131072
#define NSEG  64
#define HH    512
#define LDA   40   // padded A-LDS row (u16): 80 B, 16B-aligned, 2-way-free bank pattern

typedef unsigned short u16;
typedef unsigned int   u32;
typedef __attribute__((ext_vector_type(8))) short short8;
typedef __attribute__((ext_vector_type(8))) u16   us8;
typedef __attribute__((ext_vector_type(4))) float f32x4;
typedef __attribute__((ext_vector_type(4))) u32   u32x4;

__device__ __forceinline__ u32 f2u(float f){ union {float f; u32 u;} c; c.f=f; return c.u; }
__device__ __forceinline__ float u2f(u32 u){ union {u32 u; float f;} c; c.u=u; return c.f; }
__device__ __forceinline__ u16 bf16_rne(float f){
  u32 u = f2u(f);
  u32 r = u + 0x7FFFu + ((u >> 16) & 1u);
  return (u16)(r >> 16);
}
__device__ __forceinline__ float fast_tanh(float x){
  float e = __expf(2.0f * x);
  return 1.0f - __fdividef(2.0f, e + 1.0f);
}

// ---------------- hproj[b][j] = sum_k hidden[b][k] * W[j][k]  (coalesced; 256 blocks)
__global__ __launch_bounds__(256)
void hproj_kernel(const float* __restrict__ hidden, const float* __restrict__ W,
                  float* __restrict__ hproj)
{
  const int b    = blockIdx.x >> 2;          // segment
  const int q    = blockIdx.x & 3;           // j-quarter
  const int tid  = threadIdx.x;
  const int wave = tid >> 6;
  const int lane = tid & 63;
  const float* hrow = hidden + (size_t)b * HH + lane * 8;
  const float4 h0 = *(const float4*)(hrow);
  const float4 h1 = *(const float4*)(hrow + 4);
  for (int j = q * 128 + wave; j < q * 128 + 128; j += 4) {
    const float* wrow = W + (size_t)j * 1024 + lane * 8;
    const float4 w0 = *(const float4*)(wrow);
    const float4 w1 = *(const float4*)(wrow + 4);
    float acc = h0.x*w0.x + h0.y*w0.y + h0.z*w0.z + h0.w*w0.w
              + h1.x*w1.x + h1.y*w1.y + h1.z*w1.z + h1.w*w1.w;
    #pragma unroll
    for (int o = 32; o; o >>= 1) acc += __shfl_xor(acc, o);
    if (lane == 0) hproj[(size_t)b * HH + j] = acc;
  }
}

// ---------------- split W2 = W[:, 512:1024] into bf16 hi/lo, row-major [j][k]
__global__ __launch_bounds__(256)
void w2split_kernel(const float* __restrict__ W, u16* __restrict__ hi, u16* __restrict__ lo)
{
  const int idx = blockIdx.x * 256 + threadIdx.x;   // j*512 + k
  const int j = idx >> 9, k = idx & 511;
  const float x = W[(size_t)j * 1024 + 512 + k];
  const u32 u = f2u(x);
  hi[idx] = (u16)(u >> 16);
  lo[idx] = bf16_rne(x - u2f(u & 0xFFFF0000u));
}

// convert 16 fp32 -> 16 bf16-hi + 16 bf16-lo(trunc residual), write 2x us8 per plane
__device__ __forceinline__ void convert_write(const float* pf, u16* dh, u16* dl)
{
  union { u32x4 w; us8 s; } H0, H1, L0, L1;
  #pragma unroll
  for (int p = 0; p < 8; p++) {
    const float xa = pf[2 * p], xb = pf[2 * p + 1];
    const u32 ua = f2u(xa), ub = f2u(xb);
    const u32 h = __builtin_amdgcn_perm(ub, ua, 0x07060302u);   // [ub_hi16 | ua_hi16]
    const float ra = xa - u2f(ua & 0xFFFF0000u);
    const float rb = xb - u2f(ub & 0xFFFF0000u);
    const u32 l = __builtin_amdgcn_perm(f2u(rb), f2u(ra), 0x07060302u);
    if (p < 4) { H0.w[p] = h; L0.w[p] = l; } else { H1.w[p - 4] = h; L1.w[p - 4] = l; }
  }
  *(us8*)(dh)     = H0.s;  *(us8*)(dh + 8) = H1.s;
  *(us8*)(dl)     = L0.s;  *(us8*)(dl + 8) = L1.s;
}

// ---------------- fused GEMM: 128x256 tile, A double-buffered bf16 hi/lo in LDS
// (converted once per block during prefetch), B read straight from L2, one
// barrier per K-step with no vmcnt drain. 3-product split-bf16 MFMA + fused epilogue.
__global__ __launch_bounds__(256, 2)
void gemm_fused_kernel(const float* __restrict__ enc,
                       const u16* __restrict__ w2hi, const u16* __restrict__ w2lo,
                       const float* __restrict__ hproj, const float* __restrict__ vvec,
                       const int* __restrict__ seg, float* __restrict__ scores)
{
  __shared__ u16 sAh[2][128 * LDA];   // 20 KB
  __shared__ u16 sAl[2][128 * LDA];   // 20 KB

  const int tid  = threadIdx.x;
  const int bx   = blockIdx.x;
  const int row0 = (bx >> 1) * 128;   // col-tile fastest
  const int col0 = (bx & 1) * 256;

  const int wave = tid >> 6;
  const int lane = tid & 63;
  const int wrow = (wave >> 1) * 64;  // wave-tile 64 x 128
  const int wcol = (wave & 1) * 128;
  const int l15  = lane & 15;
  const int quad = lane >> 4;

  // A staging: thread t owns row t>>1, k-half (t&1)*16 of the 128x32 chunk
  const int sr = tid >> 1;
  const int sh = (tid & 1) * 16;
  const float* gA = enc + (size_t)(row0 + sr) * HH + sh;
  u16* const dh0 = &sAh[0][sr * LDA + sh];
  u16* const dl0 = &sAl[0][sr * LDA + sh];
  u16* const dh1 = &sAh[1][sr * LDA + sh];
  u16* const dl1 = &sAl[1][sr * LDA + sh];

  // B fragment bases (u16 index): col = col0 + wcol + j*16 + l15, k-off quad*8
  const u16* gBh = w2hi + (size_t)(col0 + wcol + l15) * HH + quad * 8;
  const u16* gBl = w2lo + (size_t)(col0 + wcol + l15) * HH + quad * 8;

  f32x4 acc[4][8];
  #pragma unroll
  for (int i = 0; i < 4; i++)
    #pragma unroll
    for (int j = 0; j < 8; j++)
      acc[i][j] = (f32x4){0.f, 0.f, 0.f, 0.f};

  // prologue: stage k=0 into buf0; prefetch k=1 into regs
  float pf[16];
  #pragma unroll
  for (int q = 0; q < 4; q++) *(float4*)&pf[4 * q] = *(const float4*)(gA + 4 * q);
  convert_write(pf, dh0, dl0);
  #pragma unroll
  for (int q = 0; q < 4; q++) *(float4*)&pf[4 * q] = *(const float4*)(gA + 32 + 4 * q);
  __syncthreads();

  for (int ks = 0; ks < HH; ks += 32) {
    const int cur = (ks >> 5) & 1;
    const u16* cAh = sAh[cur];
    const u16* cAl = sAl[cur];

    // stage k+1 into the other buffer (independent of this iter's j-loop -> overlaps MFMA)
    if (ks + 32 < HH) {
      convert_write(pf, cur ? dh0 : dh1, cur ? dl0 : dl1);
      if (ks + 64 < HH) {
        #pragma unroll
        for (int q = 0; q < 4; q++)
          *(float4*)&pf[4 * q] = *(const float4*)(gA + ks + 64 + 4 * q);
      }
    }

    // j-loop: B fragments straight from global (L2-resident), A frags from LDS
    #pragma unroll
    for (int jb = 0; jb < 2; jb++) {
      short8 bh4[4], bl4[4];
      #pragma unroll
      for (int j = 0; j < 4; j++) {
        const size_t off = (size_t)(jb * 4 + j) * 16 * HH + ks;
        bh4[j] = *(const short8*)(gBh + off);
        bl4[j] = *(const short8*)(gBl + off);
      }
      #pragma unroll
      for (int i = 0; i < 4; i++) {
        const int ar = (wrow + i * 16 + l15) * LDA + quad * 8;
        const short8 ah = *(const short8*)&cAh[ar];
        const short8 al = *(const short8*)&cAl[ar];
        #pragma unroll
        for (int j = 0; j < 4; j++) {
          acc[i][jb * 4 + j] = __builtin_amdgcn_mfma_f32_16x16x32_bf16(ah, bh4[j], acc[i][jb * 4 + j], 0, 0, 0);
          acc[i][jb * 4 + j] = __builtin_amdgcn_mfma_f32_16x16x32_bf16(al, bh4[j], acc[i][jb * 4 + j], 0, 0, 0);
          acc[i][jb * 4 + j] = __builtin_amdgcn_mfma_f32_16x16x32_bf16(ah, bl4[j], acc[i][jb * 4 + j], 0, 0, 0);
        }
      }
    }
    __syncthreads();
  }

  // ---- epilogue: + hproj, tanh, dot v, reduce over col-lanes, one atomic/row ----
  int   jn[8];
  float vv[8];
  #pragma unroll
  for (int j = 0; j < 8; j++) { jn[j] = col0 + wcol + j * 16 + l15; vv[j] = vvec[jn[j]]; }

  #pragma unroll
  for (int i = 0; i < 4; i++) {
    #pragma unroll
    for (int r = 0; r < 4; r++) {
      const int gn = row0 + wrow + i * 16 + quad * 4 + r;    // C/D: row=(lane>>4)*4+reg
      const float* hp = hproj + (size_t)seg[gn] * HH;
      float p = 0.f;
      #pragma unroll
      for (int j = 0; j < 8; j++) {
        const float c = acc[i][j][r] + hp[jn[j]];
        p += fast_tanh(c) * vv[j];
      }
      p += __shfl_xor(p, 1);
      p += __shfl_xor(p, 2);
      p += __shfl_xor(p, 4);
      p += __shfl_xor(p, 8);
      if (l15 == 0) atomicAdd(&scores[gn], p);
    }
  }
}

// ---------------- segment softmax: one block per segment (ids sorted)
__global__ __launch_bounds__(256)
void seg_softmax_kernel(const float* __restrict__ scores, const int* __restrict__ seg,
                        float* __restrict__ out)
{
  const int b    = blockIdx.x;
  const int tid  = threadIdx.x;
  const int wv   = tid >> 6;
  const int lane = tid & 63;
  __shared__ float red[4];

  int lo = 0, hi = NROWS;
  while (lo < hi) { int mid = (lo + hi) >> 1; if (seg[mid] < b) lo = mid + 1; else hi = mid; }
  const int start = lo;
  lo = 0; hi = NROWS;
  while (lo < hi) { int mid = (lo + hi) >> 1; if (seg[mid] < b + 1) lo = mid + 1; else hi = mid; }
  const int end = lo;

  float lm = -3.4e38f;
  for (int i = start + tid; i < end; i += 256) lm = fmaxf(lm, scores[i]);
  #pragma unroll
  for (int o = 32; o; o >>= 1) lm = fmaxf(lm, __shfl_xor(lm, o));
  if (lane == 0) red[wv] = lm;
  __syncthreads();
  const float gm = fmaxf(fmaxf(red[0], red[1]), fmaxf(red[2], red[3]));
  __syncthreads();

  float ls = 0.f;
  for (int i = start + tid; i < end; i += 256) ls += expf(scores[i] - gm);
  #pragma unroll
  for (int o = 32; o; o >>= 1) ls += __shfl_xor(ls, o);
  if (lane == 0) red[wv] = ls;
  __syncthreads();
  const float denom = red[0] + red[1] + red[2] + red[3];
  const float inv = 1.0f / denom;

  for (int i = start + tid; i < end; i += 256) out[i] = expf(scores[i] - gm) * inv;
}

extern "C" void kernel_launch(void* const* d_in, const int* in_sizes, int n_in,
                              void* d_out, int out_size, void* d_ws, size_t ws_size,
                              hipStream_t stream)
{
  const float* hidden = (const float*)d_in[0];
  const float* enc    = (const float*)d_in[1];
  const int*   seg    = (const int*)d_in[2];
  const float* W      = (const float*)d_in[3];
  const float* vvec   = (const float*)d_in[4];
  float* out = (float*)d_out;

  // ws layout: scores(512KB) | hproj(128KB) | w2hi(512KB) | w2lo(512KB)  ~1.7MB
  float* scores = (float*)d_ws;
  float* hproj  = scores + NROWS;
  u16*   w2hi   = (u16*)(hproj + NSEG * HH);
  u16*   w2lo   = w2hi + (size_t)HH * HH;

  hipMemsetAsync(scores, 0, NROWS * sizeof(float), stream);
  hproj_kernel<<<NSEG * 4, 256, 0, stream>>>(hidden, W, hproj);
  w2split_kernel<<<(HH * HH) / 256, 256, 0, stream>>>(W, w2hi, w2lo);
  gemm_fused_kernel<<<(NROWS / 128) * 2, 256, 0, stream>>>(enc, w2hi, w2lo,
                                                           hproj, vvec, seg, scores);
  seg_softmax_kernel<<<NSEG, 256, 0, stream>>>(scores, seg, out);
}

// Round 7
// 588.461 us; speedup vs baseline: 1.1455x; 1.1455x over previous
//
#include <hip/hip_runtime.h>
#include <math.h>

#define NROWS 131072
#define NSEG  64
#define HH    512

typedef unsigned short u16;
typedef unsigned int   u32;
typedef __attribute__((ext_vector_type(8))) short short8;
typedef __attribute__((ext_vector_type(8))) u16   us8;
typedef __attribute__((ext_vector_type(4))) float f32x4;
typedef __attribute__((ext_vector_type(4))) u32   u32x4;

__device__ __forceinline__ u32 f2u(float f){ union {float f; u32 u;} c; c.f=f; return c.u; }
__device__ __forceinline__ float u2f(u32 u){ union {u32 u; float f;} c; c.u=u; return c.f; }
__device__ __forceinline__ u16 bf16_rne(float f){
  u32 u = f2u(f);
  u32 r = u + 0x7FFFu + ((u >> 16) & 1u);
  return (u16)(r >> 16);
}
__device__ __forceinline__ float fast_tanh(float x){
  float e = __expf(2.0f * x);
  return 1.0f - __fdividef(2.0f, e + 1.0f);
}
// async 16B global->LDS; LDS dest is wave-uniform base + lane*16
__device__ __forceinline__ void gload_lds16(const void* g, void* l) {
  __builtin_amdgcn_global_load_lds((const __attribute__((address_space(1))) void*)g,
                                   (__attribute__((address_space(3))) void*)l, 16, 0, 0);
}

// ---------------- prep: blocks [0,1024) split W2 into bf16 hi/lo; blocks [1024,1280) hproj
__global__ __launch_bounds__(256)
void prep_kernel(const float* __restrict__ hidden, const float* __restrict__ W,
                 float* __restrict__ hproj, u16* __restrict__ w2hi, u16* __restrict__ w2lo)
{
  const int tid = threadIdx.x;
  if (blockIdx.x < 1024) {
    const int idx = blockIdx.x * 256 + tid;          // j*512 + k
    const int j = idx >> 9, k = idx & 511;
    const float x = W[(size_t)j * 1024 + 512 + k];
    const u32 u = f2u(x);
    w2hi[idx] = (u16)(u >> 16);
    w2lo[idx] = bf16_rne(x - u2f(u & 0xFFFF0000u));
    return;
  }
  const int bq   = blockIdx.x - 1024;
  const int b    = bq >> 2;                          // segment
  const int q    = bq & 3;                           // j-quarter
  const int wave = tid >> 6;
  const int lane = tid & 63;
  const float* hrow = hidden + (size_t)b * HH + lane * 8;
  const float4 h0 = *(const float4*)(hrow);
  const float4 h1 = *(const float4*)(hrow + 4);
  for (int j = q * 128 + wave; j < q * 128 + 128; j += 4) {
    const float* wrow = W + (size_t)j * 1024 + lane * 8;
    const float4 w0 = *(const float4*)(wrow);
    const float4 w1 = *(const float4*)(wrow + 4);
    float acc = h0.x*w0.x + h0.y*w0.y + h0.z*w0.z + h0.w*w0.w
              + h1.x*w1.x + h1.y*w1.y + h1.z*w1.z + h1.w*w1.w;
    #pragma unroll
    for (int o = 32; o; o >>= 1) acc += __shfl_xor(acc, o);
    if (lane == 0) hproj[(size_t)b * HH + j] = acc;
  }
}

// ---------------- fused GEMM: 128x256 tile, all staging pipelined 1 iter ahead.
// A: dbuf fp32 LDS (global_load_lds, XOR-swizzled), convert hi/lo in-reg (v_perm).
// B-hi: dbuf LDS (global_load_lds). B-lo: register prefetch, 1 iter ahead.
// One barrier/iter. Epilogue: 4 partial slabs, slab = (bx&1)*2 + (wave&1),
// exactly ONE writer per (slab,row) -> plain stores, no atomics.
__global__ __launch_bounds__(256, 2)
void gemm_fused_kernel(const float* __restrict__ enc,
                       const u16* __restrict__ w2hi, const u16* __restrict__ w2lo,
                       const float* __restrict__ hproj, const float* __restrict__ vvec,
                       const int* __restrict__ seg, float* __restrict__ part)
{
  __shared__ float sAf[2][128 * 32];   // 2 x 16 KB
  __shared__ u16   sBh[2][256 * 32];   // 2 x 16 KB

  const int tid  = threadIdx.x;
  const int bx   = blockIdx.x;
  const int row0 = (bx >> 1) * 128;    // col-tile fastest: A re-read by pair hits L2/L3
  const int col0 = (bx & 1) * 256;

  const int wave = tid >> 6;
  const int lane = tid & 63;
  const int wrow = (wave >> 1) * 64;   // wave-tile 64 x 128
  const int wcol = (wave & 1) * 128;
  const int l15  = lane & 15;
  const int quad = lane >> 4;

  // A staging: per issue 32 rows x 32 f32; thread t -> phys chunk t%8 of row t/8;
  // source col swizzled so reads unswizzle: logical chunk (t%8)^(row&6).
  const int arow = tid >> 3;
  const int acol = ((tid & 7) ^ (arow & 6)) * 4;
  const float* gA = enc + (size_t)(row0 + arow) * HH + acol;
  const int awb = (tid >> 6) * 256;    // wave-uniform f32 offset within issue

  // B-hi staging: per issue 64 rows x 32 u16; phys chunk t%4 of row t/4;
  // logical chunk (t%4)^((row>>1)&3).
  const int brow = tid >> 2;
  const int bcol = ((tid & 3) ^ ((brow >> 1) & 3)) * 8;
  const u16* gBh = w2hi + (size_t)(col0 + brow) * HH + bcol;
  const int bwb = (tid >> 6) * 512;    // wave-uniform u16 offset within issue

  // B-lo register fragments: col = col0 + wcol + j*16 + l15, k-off quad*8
  const u16* gBl = w2lo + (size_t)(col0 + wcol + l15) * HH + quad * 8;

  f32x4 acc[4][8];
  #pragma unroll
  for (int i = 0; i < 4; i++)
    #pragma unroll
    for (int j = 0; j < 8; j++)
      acc[i][j] = (f32x4){0.f, 0.f, 0.f, 0.f};

  // ---- prologue: stage chunk 0, prefetch B-lo(0) ----
  #pragma unroll
  for (int i = 0; i < 4; i++)
    gload_lds16(gA + (size_t)i * 32 * HH, &sAf[0][i * 1024 + awb]);
  #pragma unroll
  for (int i = 0; i < 4; i++)
    gload_lds16(gBh + (size_t)i * 64 * HH, &sBh[0][i * 2048 + bwb]);
  short8 blC[8], blN[8];
  #pragma unroll
  for (int j = 0; j < 8; j++)
    blC[j] = *(const short8*)(gBl + (size_t)j * 16 * HH);
  __syncthreads();

  for (int ks = 0; ks < HH; ks += 32) {
    const int cur = (ks >> 5) & 1;
    const int nxt = cur ^ 1;

    // ---- issue chunk k+1 staging (full compute phase in flight before the drain) ----
    if (ks + 32 < HH) {
      #pragma unroll
      for (int i = 0; i < 4; i++)
        gload_lds16(gA + (size_t)i * 32 * HH + ks + 32, &sAf[nxt][i * 1024 + awb]);
      #pragma unroll
      for (int i = 0; i < 4; i++)
        gload_lds16(gBh + (size_t)i * 64 * HH + ks + 32, &sBh[nxt][i * 2048 + bwb]);
      #pragma unroll
      for (int j = 0; j < 8; j++)
        blN[j] = *(const short8*)(gBl + (size_t)j * 16 * HH + ks + 32);
    }

    // ---- A fragments: read fp32 from LDS, split hi/lo via v_perm ----
    short8 ah[4], al[4];
    #pragma unroll
    for (int i = 0; i < 4; i++) {
      const int r  = wrow + i * 16 + l15;
      const int ab = r * 32 + (((2 * quad) ^ (r & 6))) * 4;
      const f32x4 x0 = *(const f32x4*)&sAf[cur][ab];
      const f32x4 x1 = *(const f32x4*)&sAf[cur][ab + 4];
      union { u32x4 w; short8 s; } H, L;
      #pragma unroll
      for (int p = 0; p < 4; p++) {
        const float xa = (p < 2) ? x0[2 * p] : x1[2 * p - 4];
        const float xb = (p < 2) ? x0[2 * p + 1] : x1[2 * p - 3];
        const u32 ua = f2u(xa), ub = f2u(xb);
        H.w[p] = __builtin_amdgcn_perm(ub, ua, 0x07060302u);   // [ub_hi16 | ua_hi16]
        const float ra = xa - u2f(ua & 0xFFFF0000u);
        const float rb = xb - u2f(ub & 0xFFFF0000u);
        L.w[p] = __builtin_amdgcn_perm(f2u(rb), f2u(ra), 0x07060302u);
      }
      ah[i] = H.s;
      al[i] = L.s;
    }

    // ---- j-loop: B-hi from LDS, B-lo from regs; 3-product MFMA ----
    #pragma unroll
    for (int j = 0; j < 8; j++) {
      const int rr  = wcol + j * 16 + l15;
      const int off = rr * 32 + (quad ^ ((rr >> 1) & 3)) * 8;
      const short8 bh = *(const short8*)&sBh[cur][off];
      const short8 bl = blC[j];
      #pragma unroll
      for (int i = 0; i < 4; i++) {
        acc[i][j] = __builtin_amdgcn_mfma_f32_16x16x32_bf16(ah[i], bh, acc[i][j], 0, 0, 0);
        acc[i][j] = __builtin_amdgcn_mfma_f32_16x16x32_bf16(al[i], bh, acc[i][j], 0, 0, 0);
        acc[i][j] = __builtin_amdgcn_mfma_f32_16x16x32_bf16(ah[i], bl, acc[i][j], 0, 0, 0);
      }
    }
    __syncthreads();
    #pragma unroll
    for (int j = 0; j < 8; j++) blC[j] = blN[j];
  }

  // ---- epilogue: + hproj, tanh, dot v, reduce over col-lanes, slab store ----
  int   jn[8];
  float vv[8];
  #pragma unroll
  for (int j = 0; j < 8; j++) { jn[j] = col0 + wcol + j * 16 + l15; vv[j] = vvec[jn[j]]; }

  // slab per 128-col group: (bx&1)*2 + (wave&1) -> unique writer per (slab,row)
  float* pout = part + (size_t)((bx & 1) * 2 + (wave & 1)) * NROWS;
  #pragma unroll
  for (int i = 0; i < 4; i++) {
    #pragma unroll
    for (int r = 0; r < 4; r++) {
      const int gn = row0 + wrow + i * 16 + quad * 4 + r;    // C/D: row=(lane>>4)*4+reg
      const float* hp = hproj + (size_t)seg[gn] * HH;
      float p = 0.f;
      #pragma unroll
      for (int j = 0; j < 8; j++) {
        const float c = acc[i][j][r] + hp[jn[j]];
        p += fast_tanh(c) * vv[j];
      }
      p += __shfl_xor(p, 1);
      p += __shfl_xor(p, 2);
      p += __shfl_xor(p, 4);
      p += __shfl_xor(p, 8);
      if (l15 == 0) pout[gn] = p;
    }
  }
}

// ---------------- segment softmax over sum of 4 partial slabs
__global__ __launch_bounds__(256)
void seg_softmax_kernel(const float* __restrict__ part, const int* __restrict__ seg,
                        float* __restrict__ out)
{
  const int b    = blockIdx.x;
  const int tid  = threadIdx.x;
  const int wv   = tid >> 6;
  const int lane = tid & 63;
  __shared__ float red[4];

  int lo = 0, hi = NROWS;
  while (lo < hi) { int mid = (lo + hi) >> 1; if (seg[mid] < b) lo = mid + 1; else hi = mid; }
  const int start = lo;
  lo = 0; hi = NROWS;
  while (lo < hi) { int mid = (lo + hi) >> 1; if (seg[mid] < b + 1) lo = mid + 1; else hi = mid; }
  const int end = lo;

  float lm = -3.4e38f;
  for (int i = start + tid; i < end; i += 256) {
    const float s = part[i] + part[NROWS + i] + part[2 * NROWS + i] + part[3 * NROWS + i];
    lm = fmaxf(lm, s);
  }
  #pragma unroll
  for (int o = 32; o; o >>= 1) lm = fmaxf(lm, __shfl_xor(lm, o));
  if (lane == 0) red[wv] = lm;
  __syncthreads();
  const float gm = fmaxf(fmaxf(red[0], red[1]), fmaxf(red[2], red[3]));
  __syncthreads();

  float ls = 0.f;
  for (int i = start + tid; i < end; i += 256) {
    const float s = part[i] + part[NROWS + i] + part[2 * NROWS + i] + part[3 * NROWS + i];
    ls += expf(s - gm);
  }
  #pragma unroll
  for (int o = 32; o; o >>= 1) ls += __shfl_xor(ls, o);
  if (lane == 0) red[wv] = ls;
  __syncthreads();
  const float denom = red[0] + red[1] + red[2] + red[3];
  const float inv = 1.0f / denom;

  for (int i = start + tid; i < end; i += 256) {
    const float s = part[i] + part[NROWS + i] + part[2 * NROWS + i] + part[3 * NROWS + i];
    out[i] = expf(s - gm) * inv;
  }
}

extern "C" void kernel_launch(void* const* d_in, const int* in_sizes, int n_in,
                              void* d_out, int out_size, void* d_ws, size_t ws_size,
                              hipStream_t stream)
{
  const float* hidden = (const float*)d_in[0];
  const float* enc    = (const float*)d_in[1];
  const int*   seg    = (const int*)d_in[2];
  const float* W      = (const float*)d_in[3];
  const float* vvec   = (const float*)d_in[4];
  float* out = (float*)d_out;

  // ws layout: part(4*512KB) | hproj(128KB) | w2hi(512KB) | w2lo(512KB)  ~3.2MB
  float* part  = (float*)d_ws;
  float* hproj = part + 4 * (size_t)NROWS;
  u16*   w2hi  = (u16*)(hproj + NSEG * HH);
  u16*   w2lo  = w2hi + (size_t)HH * HH;

  prep_kernel<<<1024 + NSEG * 4, 256, 0, stream>>>(hidden, W, hproj, w2hi, w2lo);
  gemm_fused_kernel<<<(NROWS / 128) * 2, 256, 0, stream>>>(enc, w2hi, w2lo,
                                                           hproj, vvec, seg, part);
  seg_softmax_kernel<<<NSEG, 256, 0, stream>>>(part, seg, out);
}